// Round 4
// baseline (696.303 us; speedup 1.0000x reference)
//
#include <hip/hip_runtime.h>
#include <hip/hip_bf16.h>
#include <math.h>

#define NN 10000
#define EE 640000
#define FF 128
#define KSPLIT 13   // 1664 = 13 * 128

// ---------------------------------------------------------------------------
// avg_log over the degree histogram (64 bins)
__global__ __launch_bounds__(64) void avglog_k(const int* __restrict__ dh,
                                               float* __restrict__ out) {
  int t = threadIdx.x;
  float v = (float)dh[t];
  float num = logf((float)t + 1.0f) * v;
#pragma unroll
  for (int off = 32; off > 0; off >>= 1) {
    num += __shfl_down(num, off);
    v   += __shfl_down(v, off);
  }
  if (t == 0) out[0] = num / v;
}

// count edges per dst node
__global__ __launch_bounds__(256) void count_k(const int* __restrict__ ei,
                                               int* __restrict__ cnt, int E) {
  int e = blockIdx.x * 256 + threadIdx.x;
  if (e < E) {
    int d = ei[2 * (size_t)e + 1];
    atomicAdd(&cnt[d], 1);
  }
}

// single-block exclusive scan over N counts -> offs[0..N], cursor copy
__global__ __launch_bounds__(1024) void scan_k(const int* __restrict__ cnt,
                                               int* __restrict__ offs,
                                               int* __restrict__ cursor, int n) {
  __shared__ int sh[1024];
  __shared__ int carry_s;
  int tid = threadIdx.x;
  if (tid == 0) carry_s = 0;
  __syncthreads();
  for (int base = 0; base < n; base += 1024) {
    int i = base + tid;
    int v = (i < n) ? cnt[i] : 0;
    sh[tid] = v;
    __syncthreads();
#pragma unroll
    for (int off = 1; off < 1024; off <<= 1) {
      int add = (tid >= off) ? sh[tid - off] : 0;
      __syncthreads();
      sh[tid] += add;
      __syncthreads();
    }
    int incl = sh[tid];
    int carry = carry_s;
    int excl = carry + incl - v;
    if (i < n) { offs[i] = excl; cursor[i] = excl; }
    int tot = sh[1023];
    __syncthreads();
    if (tid == 0) carry_s = carry + tot;
    __syncthreads();
  }
  if (tid == 0) offs[n] = carry_s;
}

// scatter edges into dst-sorted order
__global__ __launch_bounds__(256) void scatter_k(const int* __restrict__ ei,
                                                 int* __restrict__ cursor,
                                                 int* __restrict__ src_sorted,
                                                 int* __restrict__ eid_sorted, int E) {
  int e = blockIdx.x * 256 + threadIdx.x;
  if (e < E) {
    int d = ei[2 * (size_t)e + 1];
    int p = atomicAdd(&cursor[d], 1);
    src_sorted[p] = ei[2 * (size_t)e];
    eid_sorted[p] = e;
  }
}

// Wc = enc_w(16x128) @ w_ea(128x128); bc = enc_b @ w_ea + pre_b
__global__ __launch_bounds__(256) void wcomb_k(const float* __restrict__ enc_w,
                                               const float* __restrict__ enc_b,
                                               const float* __restrict__ w_ea,
                                               const float* __restrict__ pre_b,
                                               float* __restrict__ Wc,
                                               float* __restrict__ bc) {
  int o = blockIdx.x * 256 + threadIdx.x;
  if (o < 16 * 128) {
    int k = o >> 7, j = o & 127;
    float acc = 0.f;
    for (int c = 0; c < 128; ++c) acc += enc_w[k * 128 + c] * w_ea[c * 128 + j];
    Wc[o] = acc;
  } else if (o < 16 * 128 + 128) {
    int j = o - 2048;
    float acc = pre_b[j];
    for (int c = 0; c < 128; ++c) acc += enc_b[c] * w_ea[c * 128 + j];
    bc[j] = acc;
  }
}

// ---------------------------------------------------------------------------
// fp32 tiled GEMM: C(Mx128) = A(MxK) @ B(Kx128), optional K-split via blockIdx.y.
// 128 threads, 32x128 tile, 4x8 microtile, all LDS reads are b128 (2-way max
// bank aliasing = free on CDNA4).
__global__ __launch_bounds__(128) void gemm_k(const float* __restrict__ A, int lda, int Klen,
                                              const float* __restrict__ B,
                                              const float* __restrict__ bias,
                                              float* __restrict__ C, int M) {
  __shared__ float As[32][36];
  __shared__ float Bs[32][128];
  int tid = threadIdx.x;
  int kc = blockIdx.y;
  const float* Ab = A + (size_t)kc * Klen;         // column offset into A
  const float* Bb = B + (size_t)kc * Klen * 128;
  float* Cb = C + (size_t)kc * (size_t)M * 128;
  int row0 = blockIdx.x * 32;
  int tc = tid & 15;          // 16 col groups: cols {4tc..4tc+3, 64+4tc..}
  int tr = tid >> 4;          // 8 row groups of 4
  int la_r = tid >> 2;        // A-load row 0..31
  int la_k = (tid & 3) << 3;  // A-load k octet: 0,8,16,24
  int lb_c = (tid & 31) << 2;
  int lb_r = tid >> 5;        // 0..3
  float acc[4][8] = {{0.f}};

  int ar = row0 + la_r;
  if (ar >= M) ar = M - 1;
  const float* Ap = Ab + (size_t)ar * lda + la_k;

  for (int k0 = 0; k0 < Klen; k0 += 32) {
    float4 av0 = *(const float4*)(Ap + k0);
    float4 av1 = *(const float4*)(Ap + k0 + 4);
    *(float4*)&As[la_r][la_k]     = av0;
    *(float4*)&As[la_r][la_k + 4] = av1;
#pragma unroll
    for (int p = 0; p < 8; ++p) {
      int bk = lb_r + (p << 2);
      *(float4*)&Bs[bk][lb_c] = *(const float4*)(Bb + (size_t)(k0 + bk) * 128 + lb_c);
    }
    __syncthreads();
#pragma unroll
    for (int kk = 0; kk < 32; kk += 4) {
      __align__(16) float a[4][4];
#pragma unroll
      for (int r = 0; r < 4; ++r)
        *(float4*)&a[r][0] = *(const float4*)&As[tr * 4 + r][kk];
#pragma unroll
      for (int j = 0; j < 4; ++j) {
        float4 b0 = *(const float4*)&Bs[kk + j][tc << 2];
        float4 b1 = *(const float4*)&Bs[kk + j][64 + (tc << 2)];
#pragma unroll
        for (int r = 0; r < 4; ++r) {
          float av = a[r][j];
          acc[r][0] += av * b0.x; acc[r][1] += av * b0.y;
          acc[r][2] += av * b0.z; acc[r][3] += av * b0.w;
          acc[r][4] += av * b1.x; acc[r][5] += av * b1.y;
          acc[r][6] += av * b1.z; acc[r][7] += av * b1.w;
        }
      }
    }
    __syncthreads();
  }

  float4 bb0 = make_float4(0.f, 0.f, 0.f, 0.f);
  float4 bb1 = bb0;
  if (bias) {
    bb0 = *(const float4*)(bias + (tc << 2));
    bb1 = *(const float4*)(bias + 64 + (tc << 2));
  }
#pragma unroll
  for (int r = 0; r < 4; ++r) {
    int row = row0 + tr * 4 + r;
    if (row < M) {
      float4 v0 = make_float4(acc[r][0] + bb0.x, acc[r][1] + bb0.y,
                              acc[r][2] + bb0.z, acc[r][3] + bb0.w);
      float4 v1 = make_float4(acc[r][4] + bb1.x, acc[r][5] + bb1.y,
                              acc[r][6] + bb1.z, acc[r][7] + bb1.w);
      *(float4*)(Cb + (size_t)row * 128 + (tc << 2)) = v0;
      *(float4*)(Cb + (size_t)row * 128 + 64 + (tc << 2)) = v1;
    }
  }
}

// reduce KSPLIT K-split partials + bias
__global__ __launch_bounds__(256) void reduceS_k(const float* __restrict__ part,
                                                 const float* __restrict__ bias,
                                                 float* __restrict__ C) {
  int i = blockIdx.x * 256 + threadIdx.x;
  const int S = NN * 128;
  float v = bias[i & 127];
#pragma unroll
  for (int p = 0; p < KSPLIT; ++p) v += part[i + (size_t)p * S];
  C[i] = v;
}

// ---------------------------------------------------------------------------
// Fused aggregation: one block (128 threads) per node.
// m_e = hs[src] + hd[n] + ef_e @ Wc + bc ; stats -> A row [h | agg | agg*amp | agg*att]
__global__ __launch_bounds__(128) void agg_k(const float* __restrict__ h,
                                             const float* __restrict__ hs,
                                             const float* __restrict__ hd,
                                             const float* __restrict__ ef,
                                             const float* __restrict__ ew,
                                             const int* __restrict__ offs,
                                             const int* __restrict__ src_sorted,
                                             const int* __restrict__ eid_sorted,
                                             const float* __restrict__ Wc,
                                             const float* __restrict__ bc,
                                             const float* __restrict__ avg_log_p,
                                             float* __restrict__ Amat) {
  __shared__ int sbuf[128];
  __shared__ int ibuf[128];
  int n = blockIdx.x;
  int t = threadIdx.x;

  float wc[16];
#pragma unroll
  for (int k = 0; k < 16; ++k) wc[k] = Wc[k * 128 + t];

  float base = hd[(size_t)n * 128 + t] + bc[t];
  int e0 = offs[n], e1 = offs[n + 1];

  float sum = 0.f, sq = 0.f;
  float mn = 3.402823466e38f, mx = -3.402823466e38f;

  for (int c0 = e0; c0 < e1; c0 += 128) {
    int cN = e1 - c0; if (cN > 128) cN = 128;
    __syncthreads();
    if (t < cN) {
      sbuf[t] = src_sorted[c0 + t];
      ibuf[t] = eid_sorted[c0 + t];
    }
    __syncthreads();
#pragma unroll 2
    for (int i = 0; i < cN; ++i) {
      int s = sbuf[i], id = ibuf[i];
      float hv = hs[(size_t)s * 128 + t];
      float w = ew[id];
      const float4* efp = (const float4*)(ef + (size_t)id * 16);
      float4 f0 = efp[0], f1 = efp[1], f2 = efp[2], f3 = efp[3];
      float m = base + hv;
      m += f0.x * wc[0]  + f0.y * wc[1]  + f0.z * wc[2]  + f0.w * wc[3];
      m += f1.x * wc[4]  + f1.y * wc[5]  + f1.z * wc[6]  + f1.w * wc[7];
      m += f2.x * wc[8]  + f2.y * wc[9]  + f2.z * wc[10] + f2.w * wc[11];
      m += f3.x * wc[12] + f3.y * wc[13] + f3.z * wc[14] + f3.w * wc[15];
      m *= w;
      sum += m;
      sq  += m * m;
      mn = fminf(mn, m);
      mx = fmaxf(mx, m);
    }
  }

  int deg = e1 - e0;
  float fdeg = (float)deg;
  float safe = fmaxf(fdeg, 1.f);
  float mean = sum / safe;
  float var = sq / safe - mean * mean;
  float stdv = sqrtf(fmaxf(var, 0.f) + 1e-5f);
  if (deg == 0) { mn = 0.f; mx = 0.f; }

  float avg_log = avg_log_p[0];
  float logd = logf(fdeg + 1.f);
  float amp = logd / avg_log;
  float att = (deg == 0) ? 1.f : (avg_log / logd);

  float* row = Amat + (size_t)n * 1664;
  row[t] = h[(size_t)n * 128 + t];
  float a0 = mean, a1 = mn, a2 = mx, a3 = stdv;
  row[128 + t] = a0;  row[256 + t] = a1;  row[384 + t] = a2;  row[512 + t] = a3;
  row[640 + t] = a0 * amp;  row[768 + t] = a1 * amp;  row[896 + t] = a2 * amp;  row[1024 + t] = a3 * amp;
  row[1152 + t] = a0 * att; row[1280 + t] = a1 * att; row[1408 + t] = a2 * att; row[1536 + t] = a3 * att;
}

// ---------------------------------------------------------------------------
extern "C" void kernel_launch(void* const* d_in, const int* in_sizes, int n_in,
                              void* d_out, int out_size, void* d_ws, size_t ws_size,
                              hipStream_t stream) {
  (void)in_sizes; (void)n_in; (void)out_size; (void)ws_size;
  const float* x      = (const float*)d_in[0];
  const float* ef     = (const float*)d_in[1];
  const float* ew     = (const float*)d_in[2];
  const float* enc_w  = (const float*)d_in[3];
  const float* enc_b  = (const float*)d_in[4];
  const float* pre_w  = (const float*)d_in[5];
  const float* pre_b  = (const float*)d_in[6];
  const float* post_w = (const float*)d_in[7];
  const float* post_b = (const float*)d_in[8];
  const float* upd_w  = (const float*)d_in[9];
  const float* upd_b  = (const float*)d_in[10];
  const int* ei       = (const int*)d_in[11];
  const int* dh       = (const int*)d_in[12];

  char* ws = (char*)d_ws;
  size_t off = 0;
  auto alloc = [&](size_t bytes) -> void* {
    void* p = ws + off;
    off += (bytes + 255) & ~(size_t)255;
    return p;
  };
  float* avg_log    = (float*)alloc(4);
  int*   cnt        = (int*)alloc(NN * 4);
  int*   offs       = (int*)alloc((NN + 1) * 4);
  int*   cursor     = (int*)alloc(NN * 4);
  int*   src_sorted = (int*)alloc((size_t)EE * 4);
  int*   eid_sorted = (int*)alloc((size_t)EE * 4);
  float* Wc         = (float*)alloc(16 * 128 * 4);
  float* bc         = (float*)alloc(128 * 4);
  float* hs         = (float*)alloc((size_t)NN * 128 * 4);
  float* hd         = (float*)alloc((size_t)NN * 128 * 4);
  float* hbuf       = (float*)alloc((size_t)NN * 128 * 4);
  float* outb       = (float*)alloc((size_t)NN * 128 * 4);
  float* Cpart      = (float*)alloc((size_t)KSPLIT * NN * 128 * 4);
  float* Amat       = (float*)alloc((size_t)NN * 1664 * 4);

  hipMemsetAsync(cnt, 0, NN * 4, stream);
  avglog_k<<<1, 64, 0, stream>>>(dh, avg_log);
  count_k<<<(EE + 255) / 256, 256, 0, stream>>>(ei, cnt, EE);
  scan_k<<<1, 1024, 0, stream>>>(cnt, offs, cursor, NN);
  scatter_k<<<(EE + 255) / 256, 256, 0, stream>>>(ei, cursor, src_sorted, eid_sorted, EE);

  const int gx = (NN + 31) / 32;  // 313
  const float* h = x;
  for (int l = 0; l < 2; ++l) {
    const float* wl = pre_w + (size_t)l * 384 * 128;
    wcomb_k<<<9, 256, 0, stream>>>(enc_w + (size_t)l * 16 * 128, enc_b + l * 128,
                                   wl + 256 * 128, pre_b + l * 128, Wc, bc);
    gemm_k<<<dim3(gx, 1), 128, 0, stream>>>(h, 128, 128, wl, nullptr, hs, NN);
    gemm_k<<<dim3(gx, 1), 128, 0, stream>>>(h, 128, 128, wl + 128 * 128, nullptr, hd, NN);
    agg_k<<<NN, 128, 0, stream>>>(h, hs, hd, ef, ew, offs, src_sorted, eid_sorted,
                                  Wc, bc, avg_log, Amat);
    gemm_k<<<dim3(gx, KSPLIT), 128, 0, stream>>>(Amat, 1664, 128,
                                                 post_w + (size_t)l * 1664 * 128,
                                                 nullptr, Cpart, NN);
    reduceS_k<<<(NN * 128) / 256, 256, 0, stream>>>(Cpart, post_b + l * 128, outb);
    float* hn = (l == 0) ? hbuf : (float*)d_out;
    gemm_k<<<dim3(gx, 1), 128, 0, stream>>>(outb, 128, 128,
                                            upd_w + (size_t)l * 128 * 128,
                                            upd_b + l * 128, hn, NN);
    h = hbuf;
  }
}